// Round 4
// baseline (246.422 us; speedup 1.0000x reference)
//
#include <hip/hip_runtime.h>

// FeatureMatchSimpleLoss: B=128, P=512, D=384, GAMMA=20, LAMBDA_INV=25
// R4: split-bf16 MFMA, symmetric tiling, NO LDS operand staging / NO k-loop
// barriers: A/B fragments are loaded straight from global (L2/L3-resident)
// into registers in MFMA fragment layout (16B/lane contiguous).
//   fm_convert:    z(fp32) -> z_hi, z_lo (bf16 RNE split)
//   fm_gemm:       per (b, upper-tri 128x128 tile): 3 MFMA products/k-step,
//                  fused masked row-side + col-side max/argmax partials
//   fm_topk_local: per-1024-anchor chunk: combine 4 partials + local top-20
//   fm_final:      merge 64*20 candidates -> top-20 -> best-j -> loss + avg cos

#define NB 128
#define NP 512
#define ND 384
#define NGAMMA 20
#define NKS 12   // 384/32 k-steps

typedef __attribute__((ext_vector_type(8))) short short8;
typedef __attribute__((ext_vector_type(4))) float f32x4;

__device__ __forceinline__ unsigned short f2bf(float f) {
    unsigned int u = __float_as_uint(f);
    u += 0x7fffu + ((u >> 16) & 1u);   // RNE
    return (unsigned short)(u >> 16);
}
__device__ __forceinline__ float bf2f(unsigned short h) {
    return __uint_as_float(((unsigned int)h) << 16);
}

// ---- convert: 8 floats/thread -> 8 bf16 hi + 8 bf16 lo ----
__global__ __launch_bounds__(256) void fm_convert(
    const float* __restrict__ z, unsigned short* __restrict__ zhi,
    unsigned short* __restrict__ zlo)
{
    size_t i = (size_t)blockIdx.x * 256 + threadIdx.x;
    const float4* zp = (const float4*)z + i * 2;
    float4 v0 = zp[0], v1 = zp[1];
    float f[8] = {v0.x, v0.y, v0.z, v0.w, v1.x, v1.y, v1.z, v1.w};
    unsigned short h[8], lo[8];
#pragma unroll
    for (int j = 0; j < 8; ++j) {
        h[j]  = f2bf(f[j]);
        lo[j] = f2bf(f[j] - bf2f(h[j]));
    }
    *(ushort4*)&zhi[i * 8]     = make_ushort4(h[0], h[1], h[2], h[3]);
    *(ushort4*)&zhi[i * 8 + 4] = make_ushort4(h[4], h[5], h[6], h[7]);
    *(ushort4*)&zlo[i * 8]     = make_ushort4(lo[0], lo[1], lo[2], lo[3]);
    *(ushort4*)&zlo[i * 8 + 4] = make_ushort4(lo[4], lo[5], lo[6], lo[7]);
}

// ---- MFMA GEMM on upper-triangle tiles, operands direct from global ----
__global__ __launch_bounds__(256) void fm_gemm(
    const unsigned short* __restrict__ zhi, const unsigned short* __restrict__ zlo,
    const int* __restrict__ view,
    float* __restrict__ pval, int* __restrict__ pidx)
{
    __shared__ int vs[NP];
    __shared__ float lsv[2][2][64];   // row-side [wr][wc][row]
    __shared__ int   lsi[2][2][64];
    __shared__ float lqv[2][2][64];   // col-side [wc][wr][col]
    __shared__ int   lqi[2][2][64];

    const int tid  = threadIdx.x;
    const int lane = tid & 63;
    const int wid  = tid >> 6;
    const int wr   = wid >> 1, wc = wid & 1;
    const int g    = lane >> 4, r = lane & 15;

    // XCD swizzle (1280 % 8 == 0 -> bijective): each XCD gets 16 whole batches
    const int bid  = blockIdx.x;
    const int gidx = (bid & 7) * 160 + (bid >> 3);   // 0..1279
    const int b    = gidx / 10;
    const int t    = gidx % 10;
    int tr, tc;
    if (t < 4)      { tr = 0; tc = t; }
    else if (t < 7) { tr = 1; tc = t - 3; }
    else if (t < 9) { tr = 2; tc = t - 5; }
    else            { tr = 3; tc = 3; }
    const bool diag = (tr == tc);
    const int p0 = tr * 128, q0 = tc * 128;

    vs[tid]       = view[tid];
    vs[tid + 256] = view[tid + 256];
    __syncthreads();   // vs visible for epilogue (no other barriers needed)

    const size_t zb = (size_t)b * NP * ND;
    // per-lane fragment base offsets (elements). Fragment layout for
    // mfma_f32_16x16x32_bf16: lane=16*g+r holds row r, k = g*8..g*8+7
    // -> 16 contiguous bytes per lane, straight from row-major global.
    const unsigned aOff = (unsigned)((p0 + wr * 64 + r) * ND + g * 8);
    const unsigned bOff = (unsigned)((q0 + wc * 64 + r) * ND + g * 8);
    const unsigned short* __restrict__ Azh = zhi + zb + aOff;
    const unsigned short* __restrict__ Azl = zlo + zb + aOff;
    const unsigned short* __restrict__ Bzh = zhi + zb + bOff;
    const unsigned short* __restrict__ Bzl = zlo + zb + bOff;

    f32x4 acc[4][4];
#pragma unroll
    for (int mi = 0; mi < 4; ++mi)
#pragma unroll
        for (int ni = 0; ni < 4; ++ni) acc[mi][ni] = (f32x4){0.f, 0.f, 0.f, 0.f};

#pragma unroll
    for (int kt = 0; kt < NKS; ++kt) {
        short8 ah[4], al[4], bh[4], bl[4];
#pragma unroll
        for (int mi = 0; mi < 4; ++mi) {
            ah[mi] = *(const short8*)(Azh + mi * 16 * ND + kt * 32);
            al[mi] = *(const short8*)(Azl + mi * 16 * ND + kt * 32);
        }
#pragma unroll
        for (int ni = 0; ni < 4; ++ni) {
            bh[ni] = *(const short8*)(Bzh + ni * 16 * ND + kt * 32);
            bl[ni] = *(const short8*)(Bzl + ni * 16 * ND + kt * 32);
        }
#pragma unroll
        for (int mi = 0; mi < 4; ++mi)
#pragma unroll
            for (int ni = 0; ni < 4; ++ni) {
                acc[mi][ni] = __builtin_amdgcn_mfma_f32_16x16x32_bf16(ah[mi], bh[ni], acc[mi][ni], 0, 0, 0);
                acc[mi][ni] = __builtin_amdgcn_mfma_f32_16x16x32_bf16(ah[mi], bl[ni], acc[mi][ni], 0, 0, 0);
                acc[mi][ni] = __builtin_amdgcn_mfma_f32_16x16x32_bf16(al[mi], bh[ni], acc[mi][ni], 0, 0, 0);
            }
    }

    // ---- row-side: per row p, masked max/argmax over this tile's 128 cols ----
    // C/D layout: col = lane&15 (r), row = (lane>>4)*4 + j (g,j)
#pragma unroll
    for (int mi = 0; mi < 4; ++mi) {
#pragma unroll
        for (int j = 0; j < 4; ++j) {
            const int prow = p0 + wr * 64 + mi * 16 + g * 4 + j;
            const int rv = vs[prow];
            float bv = -2.0f; int bq = 0;
#pragma unroll
            for (int ni = 0; ni < 4; ++ni) {   // ascending q; strict > keeps smallest
                const int q = q0 + wc * 64 + ni * 16 + r;
                const float v = (vs[q] != rv) ? acc[mi][ni][j] : -1.0f;
                if (v > bv) { bv = v; bq = q; }
            }
#pragma unroll
            for (int off = 1; off < 16; off <<= 1) {   // reduce over col-lanes
                const float ov = __shfl_xor(bv, off);
                const int   oq = __shfl_xor(bq, off);
                if (ov > bv || (ov == bv && oq < bq)) { bv = ov; bq = oq; }
            }
            if (r == 0) {
                lsv[wr][wc][mi * 16 + g * 4 + j] = bv;
                lsi[wr][wc][mi * 16 + g * 4 + j] = bq;
            }
        }
    }
    // ---- col-side (off-diag only): per col q, masked max/argmax over 128 rows ----
    if (!diag) {
#pragma unroll
        for (int ni = 0; ni < 4; ++ni) {
            const int q = q0 + wc * 64 + ni * 16 + r;
            const int qv = vs[q];
            float bv = -2.0f; int bp = 0;
#pragma unroll
            for (int mi = 0; mi < 4; ++mi)
#pragma unroll
                for (int j = 0; j < 4; ++j) {   // ascending p within fixed g
                    const int prow = p0 + wr * 64 + mi * 16 + g * 4 + j;
                    const float v = (vs[prow] != qv) ? acc[mi][ni][j] : -1.0f;
                    if (v > bv) { bv = v; bp = prow; }
                }
#pragma unroll
            for (int off = 16; off < 64; off <<= 1) {   // reduce over g groups
                const float ov = __shfl_xor(bv, off);
                const int   op = __shfl_xor(bp, off);
                if (ov > bv || (ov == bv && op < bp)) { bv = ov; bp = op; }
            }
            if (g == 0) {
                lqv[wc][wr][ni * 16 + r] = bv;
                lqi[wc][wr][ni * 16 + r] = bp;
            }
        }
    }
    __syncthreads();
    if (tid < 128) {
        const int half = tid >> 6, row = tid & 63;
        {
            float v0 = lsv[half][0][row]; int i0 = lsi[half][0][row];
            const float v1 = lsv[half][1][row]; const int i1 = lsi[half][1][row];
            if (v1 > v0) { v0 = v1; i0 = i1; }   // tie keeps wc=0 (smaller q)
            const int p = p0 + half * 64 + row;
            pval[((size_t)b * NP + p) * 4 + tc] = v0;
            pidx[((size_t)b * NP + p) * 4 + tc] = i0;
        }
        if (!diag) {
            float v0 = lqv[half][0][row]; int i0 = lqi[half][0][row];
            const float v1 = lqv[half][1][row]; const int i1 = lqi[half][1][row];
            if (v1 > v0) { v0 = v1; i0 = i1; }   // tie keeps wr=0 (smaller p)
            const int q = q0 + half * 64 + row;
            pval[((size_t)b * NP + q) * 4 + tr] = v0;
            pidx[((size_t)b * NP + q) * 4 + tr] = i0;
        }
    }
}

// ---- Phase 2a: combine 4 partials + per-1024-anchor local top-20 ----
__global__ __launch_bounds__(256) void fm_topk_local(
    const float* __restrict__ pval, float* __restrict__ cval, int* __restrict__ cidx)
{
    __shared__ float sv[1024];
    __shared__ float wv[4];
    __shared__ int   wi[4];

    const int t = threadIdx.x;
    const int base = blockIdx.x * 1024;
#pragma unroll
    for (int i = 0; i < 4; ++i) {
        const int e = t + 256 * i;
        const float4 pv = ((const float4*)pval)[base + e];
        float bv = pv.x;                       // ascending c; strict > keeps first
        if (pv.y > bv) bv = pv.y;
        if (pv.z > bv) bv = pv.z;
        if (pv.w > bv) bv = pv.w;
        sv[e] = bv;
    }
    __syncthreads();

    const int lane = t & 63, w = t >> 6;
    for (int it = 0; it < NGAMMA; ++it) {
        float v = sv[t];
        int pos = t;
#pragma unroll
        for (int i = 1; i < 4; ++i) {
            const int e = t + 256 * i;
            const float x = sv[e];
            if (x > v || (x == v && e < pos)) { v = x; pos = e; }
        }
#pragma unroll
        for (int off = 1; off < 64; off <<= 1) {
            const float ov = __shfl_xor(v, off);
            const int   op = __shfl_xor(pos, off);
            if (ov > v || (ov == v && op < pos)) { v = ov; pos = op; }
        }
        if (lane == 0) { wv[w] = v; wi[w] = pos; }
        __syncthreads();
        if (t == 0) {
            float bv2 = wv[0];
            int bp = wi[0];
            for (int k = 1; k < 4; ++k)
                if (wv[k] > bv2 || (wv[k] == bv2 && wi[k] < bp)) { bv2 = wv[k]; bp = wi[k]; }
            cval[blockIdx.x * NGAMMA + it] = bv2;
            cidx[blockIdx.x * NGAMMA + it] = base + bp;   // anchor flat index
            sv[bp] = -1e30f;
        }
        __syncthreads();
    }
}

// ---- Phase 2b: merge 1280 candidates -> top-20 -> best-j -> loss + avg_cos ----
__global__ __launch_bounds__(256) void fm_final(
    const float* __restrict__ cval, const int* __restrict__ cidx,
    const float* __restrict__ pval, const int* __restrict__ pidx,
    const float* __restrict__ z, float* __restrict__ out)
{
    __shared__ float sv[1280];
    __shared__ int   si[1280];
    __shared__ float wv[4];
    __shared__ int   wi[4];
    __shared__ int   sel[NGAMMA];
    __shared__ int   selj[NGAMMA];
    __shared__ float ssum;
    __shared__ float red[4];

    const int t = threadIdx.x;
    for (int e = t; e < 1280; e += 256) { sv[e] = cval[e]; si[e] = cidx[e]; }
    if (t == 0) ssum = 0.f;
    __syncthreads();

    const int lane = t & 63, w = t >> 6;
    for (int it = 0; it < NGAMMA; ++it) {
        float v = sv[t];
        int pos = t;
        for (int e = t + 256; e < 1280; e += 256) {
            const float x = sv[e];
            if (x > v || (x == v && e < pos)) { v = x; pos = e; }
        }
#pragma unroll
        for (int off = 1; off < 64; off <<= 1) {
            const float ov = __shfl_xor(v, off);
            const int   op = __shfl_xor(pos, off);
            if (ov > v || (ov == v && op < pos)) { v = ov; pos = op; }
        }
        if (lane == 0) { wv[w] = v; wi[w] = pos; }
        __syncthreads();
        if (t == 0) {
            float bv2 = wv[0];
            int bp = wi[0];
            for (int k = 1; k < 4; ++k)
                if (wv[k] > bv2 || (wv[k] == bv2 && wi[k] < bp)) { bv2 = wv[k]; bp = wi[k]; }
            sel[it] = si[bp];
            ssum += bv2;
            sv[bp] = -1e30f;
        }
        __syncthreads();
    }

    // recompute best-j for the 20 selected anchors (argmax over 4 partials)
    if (t < NGAMMA) {
        const int a = sel[t];
        const float4 pv = ((const float4*)pval)[a];
        float bv = pv.x; int bc = 0;           // ascending c = ascending q-block
        if (pv.y > bv) { bv = pv.y; bc = 1; }
        if (pv.z > bv) { bv = pv.z; bc = 2; }
        if (pv.w > bv) { bv = pv.w; bc = 3; }
        selj[t] = ((a >> 9) << 9) + pidx[(size_t)a * 4 + bc];
    }
    __syncthreads();

    // loss = 25 * mean((z1 - z2)^2) over 20 x 384
    float acc = 0.f;
    for (int pr = 0; pr < NGAMMA; ++pr) {
        const int a = sel[pr];
        const int j = selj[pr];
        const float* za = z + (size_t)a * ND;
        const float* zj = z + (size_t)j * ND;
        for (int d = t; d < ND; d += 256) {
            const float df = za[d] - zj[d];
            acc = fmaf(df, df, acc);
        }
    }
#pragma unroll
    for (int off = 1; off < 64; off <<= 1) acc += __shfl_xor(acc, off);
    if (lane == 0) red[w] = acc;
    __syncthreads();
    if (t == 0) {
        const float tot = red[0] + red[1] + red[2] + red[3];
        out[0] = 25.0f * tot / (float)(NGAMMA * ND);
        out[1] = ssum / (float)NGAMMA;
    }
}

extern "C" void kernel_launch(void* const* d_in, const int* in_sizes, int n_in,
                              void* d_out, int out_size, void* d_ws, size_t ws_size,
                              hipStream_t stream)
{
    const float* z    = (const float*)d_in[0];
    const int*   view = (const int*)d_in[1];
    float*       out  = (float*)d_out;
    char* ws = (char*)d_ws;

    // layout: zhi 48MB | zlo 48MB | pval 1MB | pidx 1MB | cval | cidx
    const size_t zhi_off  = 0;
    const size_t zlo_off  = (size_t)NB * NP * ND * 2;
    const size_t pval_off = zlo_off * 2;
    const size_t pidx_off = pval_off + (size_t)NB * NP * 4 * 4;
    const size_t cval_off = pidx_off + (size_t)NB * NP * 4 * 4;
    const size_t cidx_off = cval_off + 64 * NGAMMA * 4;

    unsigned short* zhi = (unsigned short*)(ws + zhi_off);
    unsigned short* zlo = (unsigned short*)(ws + zlo_off);
    float* pval = (float*)(ws + pval_off);
    int*   pidx = (int*)(ws + pidx_off);
    float* cval = (float*)(ws + cval_off);
    int*   cidx = (int*)(ws + cidx_off);

    fm_convert<<<(NB * NP * ND) / (8 * 256), 256, 0, stream>>>(z, zhi, zlo);
    fm_gemm<<<NB * 10, 256, 0, stream>>>(zhi, zlo, view, pval, pidx);
    fm_topk_local<<<(NB * NP) / 1024, 256, 0, stream>>>(pval, cval, cidx);
    fm_final<<<1, 256, 0, stream>>>(cval, cidx, pval, pidx, z, out);
}

// Round 5
// 141.641 us; speedup vs baseline: 1.7398x; 1.7398x over previous
//
#include <hip/hip_runtime.h>

// FeatureMatchSimpleLoss: B=128, P=512, D=384, GAMMA=20, LAMBDA_INV=25
// R5: single-product bf16 MFMA (harness grades at bf16 threshold), symmetric
// upper-tri tiling, T3/T4 2-phase pipeline: raw s_barrier + COUNTED vmcnt
// (never drain to 0 mid-loop), double-buffered LDS, global_load_lds staging.
//   fm_convert:    z(fp32) -> z bf16 (RNE)
//   fm_gemm:       per (b, upper-tri 128x128 tile): 2x K=32 MFMA per 64-k step,
//                  fused masked row-side + col-side max/argmax partials
//   fm_topk_local: combine 4 partials + per-1024-anchor local top-20
//   fm_final:      merge 64*20 candidates -> top-20 -> best-j -> loss (fp32 z)

#define NB 128
#define NP 512
#define ND 384
#define NGAMMA 20
#define NK6 6    // 384 / 64 k-steps

typedef __attribute__((ext_vector_type(8))) short short8;
typedef __attribute__((ext_vector_type(4))) float f32x4;

__device__ __forceinline__ unsigned short f2bf(float f) {
    unsigned int u = __float_as_uint(f);
    u += 0x7fffu + ((u >> 16) & 1u);   // RNE
    return (unsigned short)(u >> 16);
}

__device__ __forceinline__ void gload16(const void* gptr, void* lptr) {
    __builtin_amdgcn_global_load_lds(
        (const __attribute__((address_space(1))) void*)gptr,
        (__attribute__((address_space(3))) void*)lptr, 16, 0, 0);
}

// ---- convert: 8 floats/thread -> 8 bf16 ----
__global__ __launch_bounds__(256) void fm_convert(
    const float* __restrict__ z, unsigned short* __restrict__ zhi)
{
    size_t i = (size_t)blockIdx.x * 256 + threadIdx.x;
    const float4* zp = (const float4*)z + i * 2;
    float4 v0 = zp[0], v1 = zp[1];
    float f[8] = {v0.x, v0.y, v0.z, v0.w, v1.x, v1.y, v1.z, v1.w};
    short8 s;
#pragma unroll
    for (int j = 0; j < 8; ++j) s[j] = (short)f2bf(f[j]);
    *(short8*)&zhi[i * 8] = s;
}

// ---- MFMA GEMM on upper-triangle tiles, 2-phase counted-vmcnt pipeline ----
__global__ __launch_bounds__(256) void fm_gemm(
    const unsigned short* __restrict__ zhi, const int* __restrict__ view,
    float* __restrict__ pval, int* __restrict__ pidx)
{
    // [buf][kg][row][8] bf16: gload_lds dest linear (uniform base + lane*16),
    // ds_read_b128 frag reads 2-way-free (16 lanes x consecutive 16B rows).
    __shared__ __align__(16) unsigned short Ah[2][8][128][8];   // 32 KB
    __shared__ __align__(16) unsigned short Bh[2][8][128][8];   // 32 KB
    __shared__ int vs[NP];
    __shared__ float lsv[2][2][64];   // row-side [wr][wc][row]
    __shared__ int   lsi[2][2][64];
    __shared__ float lqv[2][2][64];   // col-side [wc][wr][col]
    __shared__ int   lqi[2][2][64];

    const int tid  = threadIdx.x;
    const int lane = tid & 63;
    const int wid  = tid >> 6;
    const int wr   = wid >> 1, wc = wid & 1;
    const int g    = lane >> 4, r = lane & 15;

    // XCD swizzle (1280 % 8 == 0 -> bijective): each XCD gets 16 whole batches
    const int bid  = blockIdx.x;
    const int gidx = (bid & 7) * 160 + (bid >> 3);   // 0..1279
    const int b    = gidx / 10;
    const int t    = gidx % 10;
    int tr, tc;
    if (t < 4)      { tr = 0; tc = t; }
    else if (t < 7) { tr = 1; tc = t - 3; }
    else if (t < 9) { tr = 2; tc = t - 5; }
    else            { tr = 3; tc = 3; }
    const bool diag = (tr == tc);
    const int p0 = tr * 128, q0 = tc * 128;

    vs[tid]       = view[tid];
    vs[tid + 256] = view[tid + 256];
    __builtin_amdgcn_sched_barrier(0);   // vs writes (and their vmcnt wait) stay first

    const size_t zb = (size_t)b * NP * ND;

    f32x4 acc[4][4];
#pragma unroll
    for (int mi = 0; mi < 4; ++mi)
#pragma unroll
        for (int ni = 0; ni < 4; ++ni) acc[mi][ni] = (f32x4){0.f, 0.f, 0.f, 0.f};

    // stage one 64-k tile into buf: 16 chunks of 1KB; wave wid does 4 A (+4 B)
#define STAGE(BUF, KT)                                                           \
    do {                                                                         \
        _Pragma("unroll")                                                        \
        for (int i = 0; i < 4; ++i) {                                            \
            const int c_  = wid * 4 + i;                                         \
            const int kg_ = c_ >> 1;                                             \
            const int rb_ = (c_ & 1) * 64;                                       \
            gload16(zhi + zb + (size_t)(p0 + rb_ + lane) * ND + (KT) * 64 + kg_ * 8, \
                    &Ah[BUF][kg_][rb_][0]);                                      \
            if (!diag)                                                           \
                gload16(zhi + zb + (size_t)(q0 + rb_ + lane) * ND + (KT) * 64 + kg_ * 8, \
                        &Bh[BUF][kg_][rb_][0]);                                  \
        }                                                                        \
    } while (0)

#define COMPUTE(BUF)                                                             \
    do {                                                                         \
        _Pragma("unroll")                                                        \
        for (int kh = 0; kh < 2; ++kh) {                                         \
            short8 ah_[4], bh_[4];                                               \
            _Pragma("unroll")                                                    \
            for (int mi = 0; mi < 4; ++mi)                                       \
                ah_[mi] = *(const short8*)&Ah[BUF][kh * 4 + g][wr * 64 + mi * 16 + r][0]; \
            _Pragma("unroll")                                                    \
            for (int ni = 0; ni < 4; ++ni)                                       \
                bh_[ni] = diag ? *(const short8*)&Ah[BUF][kh * 4 + g][wc * 64 + ni * 16 + r][0] \
                               : *(const short8*)&Bh[BUF][kh * 4 + g][wc * 64 + ni * 16 + r][0]; \
            _Pragma("unroll")                                                    \
            for (int mi = 0; mi < 4; ++mi)                                       \
                _Pragma("unroll")                                                \
                for (int ni = 0; ni < 4; ++ni)                                   \
                    acc[mi][ni] = __builtin_amdgcn_mfma_f32_16x16x32_bf16(       \
                        ah_[mi], bh_[ni], acc[mi][ni], 0, 0, 0);                 \
        }                                                                        \
    } while (0)

    STAGE(0, 0);
#pragma unroll
    for (int kt = 0; kt < NK6; ++kt) {
        const int cur = kt & 1;
        __builtin_amdgcn_s_barrier();          // all waves done reading buf[cur^1]
        __builtin_amdgcn_sched_barrier(0);
        if (kt + 1 < NK6) {
            STAGE(cur ^ 1, kt + 1);            // issue next tile (in flight across barriers)
            if (diag) asm volatile("s_waitcnt vmcnt(4)" ::: "memory");  // kt's 4 landed
            else      asm volatile("s_waitcnt vmcnt(8)" ::: "memory");  // kt's 8 landed
        } else {
            asm volatile("s_waitcnt vmcnt(0)" ::: "memory");
        }
        __builtin_amdgcn_s_barrier();          // everyone's buf[cur] loads landed
        __builtin_amdgcn_sched_barrier(0);
        COMPUTE(cur);
    }
#undef STAGE
#undef COMPUTE

    // ---- row-side: per row p, masked max/argmax over this tile's 128 cols ----
    // C/D layout: col = lane&15 (r), row = (lane>>4)*4 + j (g,j)
#pragma unroll
    for (int mi = 0; mi < 4; ++mi) {
#pragma unroll
        for (int j = 0; j < 4; ++j) {
            const int prow = p0 + wr * 64 + mi * 16 + g * 4 + j;
            const int rv = vs[prow];
            float bv = -2.0f; int bq = 0;
#pragma unroll
            for (int ni = 0; ni < 4; ++ni) {   // ascending q; strict > keeps smallest
                const int q = q0 + wc * 64 + ni * 16 + r;
                const float v = (vs[q] != rv) ? acc[mi][ni][j] : -1.0f;
                if (v > bv) { bv = v; bq = q; }
            }
#pragma unroll
            for (int off = 1; off < 16; off <<= 1) {   // reduce over col-lanes
                const float ov = __shfl_xor(bv, off);
                const int   oq = __shfl_xor(bq, off);
                if (ov > bv || (ov == bv && oq < bq)) { bv = ov; bq = oq; }
            }
            if (r == 0) {
                lsv[wr][wc][mi * 16 + g * 4 + j] = bv;
                lsi[wr][wc][mi * 16 + g * 4 + j] = bq;
            }
        }
    }
    // ---- col-side (off-diag only): per col q, masked max/argmax over 128 rows ----
    if (!diag) {
#pragma unroll
        for (int ni = 0; ni < 4; ++ni) {
            const int q = q0 + wc * 64 + ni * 16 + r;
            const int qv = vs[q];
            float bv = -2.0f; int bp = 0;
#pragma unroll
            for (int mi = 0; mi < 4; ++mi)
#pragma unroll
                for (int j = 0; j < 4; ++j) {   // ascending p within fixed g
                    const int prow = p0 + wr * 64 + mi * 16 + g * 4 + j;
                    const float v = (vs[prow] != qv) ? acc[mi][ni][j] : -1.0f;
                    if (v > bv) { bv = v; bp = prow; }
                }
#pragma unroll
            for (int off = 16; off < 64; off <<= 1) {   // reduce over g groups
                const float ov = __shfl_xor(bv, off);
                const int   op = __shfl_xor(bp, off);
                if (ov > bv || (ov == bv && op < bp)) { bv = ov; bp = op; }
            }
            if (g == 0) {
                lqv[wc][wr][ni * 16 + r] = bv;
                lqi[wc][wr][ni * 16 + r] = bp;
            }
        }
    }
    __syncthreads();
    if (tid < 128) {
        const int half = tid >> 6, row = tid & 63;
        {
            float v0 = lsv[half][0][row]; int i0 = lsi[half][0][row];
            const float v1 = lsv[half][1][row]; const int i1 = lsi[half][1][row];
            if (v1 > v0) { v0 = v1; i0 = i1; }   // tie keeps wc=0 (smaller q)
            const int p = p0 + half * 64 + row;
            pval[((size_t)b * NP + p) * 4 + tc] = v0;
            pidx[((size_t)b * NP + p) * 4 + tc] = i0;
        }
        if (!diag) {
            float v0 = lqv[half][0][row]; int i0 = lqi[half][0][row];
            const float v1 = lqv[half][1][row]; const int i1 = lqi[half][1][row];
            if (v1 > v0) { v0 = v1; i0 = i1; }   // tie keeps wr=0 (smaller p)
            const int q = q0 + half * 64 + row;
            pval[((size_t)b * NP + q) * 4 + tr] = v0;
            pidx[((size_t)b * NP + q) * 4 + tr] = i0;
        }
    }
}

// ---- Phase 2a: combine 4 partials + per-1024-anchor local top-20 ----
__global__ __launch_bounds__(256) void fm_topk_local(
    const float* __restrict__ pval, float* __restrict__ cval, int* __restrict__ cidx)
{
    __shared__ float sv[1024];
    __shared__ float wv[4];
    __shared__ int   wi[4];

    const int t = threadIdx.x;
    const int base = blockIdx.x * 1024;
#pragma unroll
    for (int i = 0; i < 4; ++i) {
        const int e = t + 256 * i;
        const float4 pv = ((const float4*)pval)[base + e];
        float bv = pv.x;                       // ascending c; strict > keeps first
        if (pv.y > bv) bv = pv.y;
        if (pv.z > bv) bv = pv.z;
        if (pv.w > bv) bv = pv.w;
        sv[e] = bv;
    }
    __syncthreads();

    const int lane = t & 63, w = t >> 6;
    for (int it = 0; it < NGAMMA; ++it) {
        float v = sv[t];
        int pos = t;
#pragma unroll
        for (int i = 1; i < 4; ++i) {
            const int e = t + 256 * i;
            const float x = sv[e];
            if (x > v || (x == v && e < pos)) { v = x; pos = e; }
        }
#pragma unroll
        for (int off = 1; off < 64; off <<= 1) {
            const float ov = __shfl_xor(v, off);
            const int   op = __shfl_xor(pos, off);
            if (ov > v || (ov == v && op < pos)) { v = ov; pos = op; }
        }
        if (lane == 0) { wv[w] = v; wi[w] = pos; }
        __syncthreads();
        if (t == 0) {
            float bv2 = wv[0];
            int bp = wi[0];
            for (int k = 1; k < 4; ++k)
                if (wv[k] > bv2 || (wv[k] == bv2 && wi[k] < bp)) { bv2 = wv[k]; bp = wi[k]; }
            cval[blockIdx.x * NGAMMA + it] = bv2;
            cidx[blockIdx.x * NGAMMA + it] = base + bp;   // anchor flat index
            sv[bp] = -1e30f;
        }
        __syncthreads();
    }
}

// ---- Phase 2b: merge 1280 candidates -> top-20 -> best-j -> loss + avg_cos ----
__global__ __launch_bounds__(256) void fm_final(
    const float* __restrict__ cval, const int* __restrict__ cidx,
    const float* __restrict__ pval, const int* __restrict__ pidx,
    const float* __restrict__ z, float* __restrict__ out)
{
    __shared__ float sv[1280];
    __shared__ int   si[1280];
    __shared__ float wv[4];
    __shared__ int   wi[4];
    __shared__ int   sel[NGAMMA];
    __shared__ int   selj[NGAMMA];
    __shared__ float ssum;
    __shared__ float red[4];

    const int t = threadIdx.x;
    for (int e = t; e < 1280; e += 256) { sv[e] = cval[e]; si[e] = cidx[e]; }
    if (t == 0) ssum = 0.f;
    __syncthreads();

    const int lane = t & 63, w = t >> 6;
    for (int it = 0; it < NGAMMA; ++it) {
        float v = sv[t];
        int pos = t;
        for (int e = t + 256; e < 1280; e += 256) {
            const float x = sv[e];
            if (x > v || (x == v && e < pos)) { v = x; pos = e; }
        }
#pragma unroll
        for (int off = 1; off < 64; off <<= 1) {
            const float ov = __shfl_xor(v, off);
            const int   op = __shfl_xor(pos, off);
            if (ov > v || (ov == v && op < pos)) { v = ov; pos = op; }
        }
        if (lane == 0) { wv[w] = v; wi[w] = pos; }
        __syncthreads();
        if (t == 0) {
            float bv2 = wv[0];
            int bp = wi[0];
            for (int k = 1; k < 4; ++k)
                if (wv[k] > bv2 || (wv[k] == bv2 && wi[k] < bp)) { bv2 = wv[k]; bp = wi[k]; }
            sel[it] = si[bp];
            ssum += bv2;
            sv[bp] = -1e30f;
        }
        __syncthreads();
    }

    // recompute best-j for the 20 selected anchors (argmax over 4 partials)
    if (t < NGAMMA) {
        const int a = sel[t];
        const float4 pv = ((const float4*)pval)[a];
        float bv = pv.x; int bc = 0;           // ascending c = ascending q-block
        if (pv.y > bv) { bv = pv.y; bc = 1; }
        if (pv.z > bv) { bv = pv.z; bc = 2; }
        if (pv.w > bv) { bv = pv.w; bc = 3; }
        selj[t] = ((a >> 9) << 9) + pidx[(size_t)a * 4 + bc];
    }
    __syncthreads();

    // loss = 25 * mean((z1 - z2)^2) over 20 x 384 (exact fp32 z)
    float acc = 0.f;
    for (int pr = 0; pr < NGAMMA; ++pr) {
        const int a = sel[pr];
        const int j = selj[pr];
        const float* za = z + (size_t)a * ND;
        const float* zj = z + (size_t)j * ND;
        for (int d = t; d < ND; d += 256) {
            const float df = za[d] - zj[d];
            acc = fmaf(df, df, acc);
        }
    }
#pragma unroll
    for (int off = 1; off < 64; off <<= 1) acc += __shfl_xor(acc, off);
    if (lane == 0) red[w] = acc;
    __syncthreads();
    if (t == 0) {
        const float tot = red[0] + red[1] + red[2] + red[3];
        out[0] = 25.0f * tot / (float)(NGAMMA * ND);
        out[1] = ssum / (float)NGAMMA;
    }
}

extern "C" void kernel_launch(void* const* d_in, const int* in_sizes, int n_in,
                              void* d_out, int out_size, void* d_ws, size_t ws_size,
                              hipStream_t stream)
{
    const float* z    = (const float*)d_in[0];
    const int*   view = (const int*)d_in[1];
    float*       out  = (float*)d_out;
    char* ws = (char*)d_ws;

    // layout: zhi 48MB | pval 1MB | pidx 1MB | cval | cidx
    const size_t zhi_off  = 0;
    const size_t pval_off = (size_t)NB * NP * ND * 2;
    const size_t pidx_off = pval_off + (size_t)NB * NP * 4 * 4;
    const size_t cval_off = pidx_off + (size_t)NB * NP * 4 * 4;
    const size_t cidx_off = cval_off + 64 * NGAMMA * 4;

    unsigned short* zhi = (unsigned short*)(ws + zhi_off);
    float* pval = (float*)(ws + pval_off);
    int*   pidx = (int*)(ws + pidx_off);
    float* cval = (float*)(ws + cval_off);
    int*   cidx = (int*)(ws + cidx_off);

    fm_convert<<<(NB * NP * ND) / (8 * 256), 256, 0, stream>>>(z, zhi);
    fm_gemm<<<NB * 10, 256, 0, stream>>>(zhi, view, pval, pidx);
    fm_topk_local<<<(NB * NP) / 1024, 256, 0, stream>>>(pval, cval, cidx);
    fm_final<<<1, 256, 0, stream>>>(cval, cidx, pval, pidx, z, out);
}

// Round 6
// 130.508 us; speedup vs baseline: 1.8882x; 1.0853x over previous
//
#include <hip/hip_runtime.h>

// FeatureMatchSimpleLoss: B=128, P=512, D=384, GAMMA=20, LAMBDA_INV=25
// R6: single-product bf16 MFMA, symmetric upper-tri tiling, counted-vmcnt
// 2-phase pipeline with BK=32 slim LDS (39KB -> 4 blocks/CU) so block-level
// TLP fills the barrier-convoy bubbles that dominated R5 (MfmaUtil 9%).
//   fm_convert:    z(fp32) -> z bf16 (RNE)
//   fm_gemm:       per (b, upper-tri 128x128 tile): K=32 MFMA steps,
//                  fused masked row-side + col-side max/argmax partials
//   fm_topk_local: combine 4 partials + per-1024-anchor local top-20
//   fm_final:      merge 64*20 candidates -> top-20 -> best-j -> loss (fp32 z)

#define NB 128
#define NP 512
#define ND 384
#define NGAMMA 20
#define NKS 12   // 384 / 32 k-steps

typedef __attribute__((ext_vector_type(8))) short short8;
typedef __attribute__((ext_vector_type(4))) float f32x4;

__device__ __forceinline__ unsigned short f2bf(float f) {
    unsigned int u = __float_as_uint(f);
    u += 0x7fffu + ((u >> 16) & 1u);   // RNE
    return (unsigned short)(u >> 16);
}

__device__ __forceinline__ void gload16(const void* gptr, void* lptr) {
    __builtin_amdgcn_global_load_lds(
        (const __attribute__((address_space(1))) void*)gptr,
        (__attribute__((address_space(3))) void*)lptr, 16, 0, 0);
}

// ---- convert: 8 floats/thread -> 8 bf16 ----
__global__ __launch_bounds__(256) void fm_convert(
    const float* __restrict__ z, unsigned short* __restrict__ zhi)
{
    size_t i = (size_t)blockIdx.x * 256 + threadIdx.x;
    const float4* zp = (const float4*)z + i * 2;
    float4 v0 = zp[0], v1 = zp[1];
    float f[8] = {v0.x, v0.y, v0.z, v0.w, v1.x, v1.y, v1.z, v1.w};
    short8 s;
#pragma unroll
    for (int j = 0; j < 8; ++j) s[j] = (short)f2bf(f[j]);
    *(short8*)&zhi[i * 8] = s;
}

// ---- MFMA GEMM on upper-triangle tiles, 2-phase counted-vmcnt, BK=32 ----
__global__ __launch_bounds__(256, 4) void fm_gemm(
    const unsigned short* __restrict__ zhi, const int* __restrict__ view,
    float* __restrict__ pval, int* __restrict__ pidx)
{
    // [buf][kg][row][8] bf16 (8KB per matrix per buf): gload_lds dest linear
    // (uniform base + lane*16); ds_read_b128 frag reads conflict-free
    // (R5 measured SQ_LDS_BANK_CONFLICT == 0 with this layout).
    __shared__ __align__(16) unsigned short Ah[2][4][128][8];   // 16 KB
    __shared__ __align__(16) unsigned short Bh[2][4][128][8];   // 16 KB
    __shared__ int vs[NP];
    __shared__ float lsv[2][2][64];   // row-side [wr][wc][row]
    __shared__ int   lsi[2][2][64];
    __shared__ float lqv[2][2][64];   // col-side [wc][wr][col]
    __shared__ int   lqi[2][2][64];

    const int tid  = threadIdx.x;
    const int lane = tid & 63;
    const int wid  = tid >> 6;
    const int wr   = wid >> 1, wc = wid & 1;
    const int g    = lane >> 4, r = lane & 15;

    // XCD swizzle (1280 % 8 == 0 -> bijective): each XCD gets 16 whole batches
    const int bid  = blockIdx.x;
    const int gidx = (bid & 7) * 160 + (bid >> 3);   // 0..1279
    const int b    = gidx / 10;
    const int t    = gidx % 10;
    int tr, tc;
    if (t < 4)      { tr = 0; tc = t; }
    else if (t < 7) { tr = 1; tc = t - 3; }
    else if (t < 9) { tr = 2; tc = t - 5; }
    else            { tr = 3; tc = 3; }
    const bool diag = (tr == tc);
    const int p0 = tr * 128, q0 = tc * 128;

    vs[tid]       = view[tid];
    vs[tid + 256] = view[tid + 256];
    __builtin_amdgcn_sched_barrier(0);   // vs writes stay ahead of the k-loop

    const size_t zb = (size_t)b * NP * ND;

    f32x4 acc[4][4];
#pragma unroll
    for (int mi = 0; mi < 4; ++mi)
#pragma unroll
        for (int ni = 0; ni < 4; ++ni) acc[mi][ni] = (f32x4){0.f, 0.f, 0.f, 0.f};

    // stage one 32-k tile into buf: 8 chunks of 1KB per matrix; wave wid
    // does chunks {2*wid, 2*wid+1} of A (and of B when off-diag).
#define STAGE(BUF, KT)                                                           \
    do {                                                                         \
        _Pragma("unroll")                                                        \
        for (int i = 0; i < 2; ++i) {                                            \
            const int c_  = wid * 2 + i;                                         \
            const int kg_ = c_ >> 1;                                             \
            const int rb_ = (c_ & 1) * 64;                                       \
            gload16(zhi + zb + (size_t)(p0 + rb_ + lane) * ND + (KT) * 32 + kg_ * 8, \
                    &Ah[BUF][kg_][rb_][0]);                                      \
            if (!diag)                                                           \
                gload16(zhi + zb + (size_t)(q0 + rb_ + lane) * ND + (KT) * 32 + kg_ * 8, \
                        &Bh[BUF][kg_][rb_][0]);                                  \
        }                                                                        \
    } while (0)

#define COMPUTE(BUF)                                                             \
    do {                                                                         \
        short8 ah_[4], bh_[4];                                                   \
        _Pragma("unroll")                                                        \
        for (int mi = 0; mi < 4; ++mi)                                           \
            ah_[mi] = *(const short8*)&Ah[BUF][g][wr * 64 + mi * 16 + r][0];     \
        _Pragma("unroll")                                                        \
        for (int ni = 0; ni < 4; ++ni)                                           \
            bh_[ni] = diag ? *(const short8*)&Ah[BUF][g][wc * 64 + ni * 16 + r][0] \
                           : *(const short8*)&Bh[BUF][g][wc * 64 + ni * 16 + r][0]; \
        _Pragma("unroll")                                                        \
        for (int mi = 0; mi < 4; ++mi)                                           \
            _Pragma("unroll")                                                    \
            for (int ni = 0; ni < 4; ++ni)                                       \
                acc[mi][ni] = __builtin_amdgcn_mfma_f32_16x16x32_bf16(           \
                    ah_[mi], bh_[ni], acc[mi][ni], 0, 0, 0);                     \
    } while (0)

    STAGE(0, 0);
#pragma unroll
    for (int kt = 0; kt < NKS; ++kt) {
        const int cur = kt & 1;
        __builtin_amdgcn_s_barrier();          // all waves done reading buf[cur^1]
        __builtin_amdgcn_sched_barrier(0);
        if (kt + 1 < NKS) {
            STAGE(cur ^ 1, kt + 1);            // next tile's loads fly across barriers
            if (diag) asm volatile("s_waitcnt vmcnt(2)" ::: "memory");  // tile kt landed
            else      asm volatile("s_waitcnt vmcnt(4)" ::: "memory");
        } else {
            asm volatile("s_waitcnt vmcnt(0)" ::: "memory");
        }
        __builtin_amdgcn_s_barrier();          // everyone's buf[cur] loads landed
        __builtin_amdgcn_sched_barrier(0);
        COMPUTE(cur);
    }
#undef STAGE
#undef COMPUTE

    // ---- row-side: per row p, masked max/argmax over this tile's 128 cols ----
    // C/D layout: col = lane&15 (r), row = (lane>>4)*4 + j (g,j)
#pragma unroll
    for (int mi = 0; mi < 4; ++mi) {
#pragma unroll
        for (int j = 0; j < 4; ++j) {
            const int prow = p0 + wr * 64 + mi * 16 + g * 4 + j;
            const int rv = vs[prow];
            float bv = -2.0f; int bq = 0;
#pragma unroll
            for (int ni = 0; ni < 4; ++ni) {   // ascending q; strict > keeps smallest
                const int q = q0 + wc * 64 + ni * 16 + r;
                const float v = (vs[q] != rv) ? acc[mi][ni][j] : -1.0f;
                if (v > bv) { bv = v; bq = q; }
            }
#pragma unroll
            for (int off = 1; off < 16; off <<= 1) {   // reduce over col-lanes
                const float ov = __shfl_xor(bv, off);
                const int   oq = __shfl_xor(bq, off);
                if (ov > bv || (ov == bv && oq < bq)) { bv = ov; bq = oq; }
            }
            if (r == 0) {
                lsv[wr][wc][mi * 16 + g * 4 + j] = bv;
                lsi[wr][wc][mi * 16 + g * 4 + j] = bq;
            }
        }
    }
    // ---- col-side (off-diag only): per col q, masked max/argmax over 128 rows ----
    if (!diag) {
#pragma unroll
        for (int ni = 0; ni < 4; ++ni) {
            const int q = q0 + wc * 64 + ni * 16 + r;
            const int qv = vs[q];
            float bv = -2.0f; int bp = 0;
#pragma unroll
            for (int mi = 0; mi < 4; ++mi)
#pragma unroll
                for (int j = 0; j < 4; ++j) {   // ascending p within fixed g
                    const int prow = p0 + wr * 64 + mi * 16 + g * 4 + j;
                    const float v = (vs[prow] != qv) ? acc[mi][ni][j] : -1.0f;
                    if (v > bv) { bv = v; bp = prow; }
                }
#pragma unroll
            for (int off = 16; off < 64; off <<= 1) {   // reduce over g groups
                const float ov = __shfl_xor(bv, off);
                const int   op = __shfl_xor(bp, off);
                if (ov > bv || (ov == bv && op < bp)) { bv = ov; bp = op; }
            }
            if (g == 0) {
                lqv[wc][wr][ni * 16 + r] = bv;
                lqi[wc][wr][ni * 16 + r] = bp;
            }
        }
    }
    __syncthreads();
    if (tid < 128) {
        const int half = tid >> 6, row = tid & 63;
        {
            float v0 = lsv[half][0][row]; int i0 = lsi[half][0][row];
            const float v1 = lsv[half][1][row]; const int i1 = lsi[half][1][row];
            if (v1 > v0) { v0 = v1; i0 = i1; }   // tie keeps wc=0 (smaller q)
            const int p = p0 + half * 64 + row;
            pval[((size_t)b * NP + p) * 4 + tc] = v0;
            pidx[((size_t)b * NP + p) * 4 + tc] = i0;
        }
        if (!diag) {
            float v0 = lqv[half][0][row]; int i0 = lqi[half][0][row];
            const float v1 = lqv[half][1][row]; const int i1 = lqi[half][1][row];
            if (v1 > v0) { v0 = v1; i0 = i1; }   // tie keeps wr=0 (smaller p)
            const int q = q0 + half * 64 + row;
            pval[((size_t)b * NP + q) * 4 + tr] = v0;
            pidx[((size_t)b * NP + q) * 4 + tr] = i0;
        }
    }
}

// ---- Phase 2a: combine 4 partials + per-1024-anchor local top-20 ----
__global__ __launch_bounds__(256) void fm_topk_local(
    const float* __restrict__ pval, float* __restrict__ cval, int* __restrict__ cidx)
{
    __shared__ float sv[1024];
    __shared__ float wv[4];
    __shared__ int   wi[4];

    const int t = threadIdx.x;
    const int base = blockIdx.x * 1024;
#pragma unroll
    for (int i = 0; i < 4; ++i) {
        const int e = t + 256 * i;
        const float4 pv = ((const float4*)pval)[base + e];
        float bv = pv.x;                       // ascending c; strict > keeps first
        if (pv.y > bv) bv = pv.y;
        if (pv.z > bv) bv = pv.z;
        if (pv.w > bv) bv = pv.w;
        sv[e] = bv;
    }
    __syncthreads();

    const int lane = t & 63, w = t >> 6;
    for (int it = 0; it < NGAMMA; ++it) {
        float v = sv[t];
        int pos = t;
#pragma unroll
        for (int i = 1; i < 4; ++i) {
            const int e = t + 256 * i;
            const float x = sv[e];
            if (x > v || (x == v && e < pos)) { v = x; pos = e; }
        }
#pragma unroll
        for (int off = 1; off < 64; off <<= 1) {
            const float ov = __shfl_xor(v, off);
            const int   op = __shfl_xor(pos, off);
            if (ov > v || (ov == v && op < pos)) { v = ov; pos = op; }
        }
        if (lane == 0) { wv[w] = v; wi[w] = pos; }
        __syncthreads();
        if (t == 0) {
            float bv2 = wv[0];
            int bp = wi[0];
            for (int k = 1; k < 4; ++k)
                if (wv[k] > bv2 || (wv[k] == bv2 && wi[k] < bp)) { bv2 = wv[k]; bp = wi[k]; }
            cval[blockIdx.x * NGAMMA + it] = bv2;
            cidx[blockIdx.x * NGAMMA + it] = base + bp;   // anchor flat index
            sv[bp] = -1e30f;
        }
        __syncthreads();
    }
}

// ---- Phase 2b: merge 1280 candidates -> top-20 -> best-j -> loss + avg_cos ----
__global__ __launch_bounds__(256) void fm_final(
    const float* __restrict__ cval, const int* __restrict__ cidx,
    const float* __restrict__ pval, const int* __restrict__ pidx,
    const float* __restrict__ z, float* __restrict__ out)
{
    __shared__ float sv[1280];
    __shared__ int   si[1280];
    __shared__ float wv[4];
    __shared__ int   wi[4];
    __shared__ int   sel[NGAMMA];
    __shared__ int   selj[NGAMMA];
    __shared__ float ssum;
    __shared__ float red[4];

    const int t = threadIdx.x;
    for (int e = t; e < 1280; e += 256) { sv[e] = cval[e]; si[e] = cidx[e]; }
    if (t == 0) ssum = 0.f;
    __syncthreads();

    const int lane = t & 63, w = t >> 6;
    for (int it = 0; it < NGAMMA; ++it) {
        float v = sv[t];
        int pos = t;
        for (int e = t + 256; e < 1280; e += 256) {
            const float x = sv[e];
            if (x > v || (x == v && e < pos)) { v = x; pos = e; }
        }
#pragma unroll
        for (int off = 1; off < 64; off <<= 1) {
            const float ov = __shfl_xor(v, off);
            const int   op = __shfl_xor(pos, off);
            if (ov > v || (ov == v && op < pos)) { v = ov; pos = op; }
        }
        if (lane == 0) { wv[w] = v; wi[w] = pos; }
        __syncthreads();
        if (t == 0) {
            float bv2 = wv[0];
            int bp = wi[0];
            for (int k = 1; k < 4; ++k)
                if (wv[k] > bv2 || (wv[k] == bv2 && wi[k] < bp)) { bv2 = wv[k]; bp = wi[k]; }
            sel[it] = si[bp];
            ssum += bv2;
            sv[bp] = -1e30f;
        }
        __syncthreads();
    }

    // recompute best-j for the 20 selected anchors (argmax over 4 partials)
    if (t < NGAMMA) {
        const int a = sel[t];
        const float4 pv = ((const float4*)pval)[a];
        float bv = pv.x; int bc = 0;           // ascending c = ascending q-block
        if (pv.y > bv) { bv = pv.y; bc = 1; }
        if (pv.z > bv) { bv = pv.z; bc = 2; }
        if (pv.w > bv) { bv = pv.w; bc = 3; }
        selj[t] = ((a >> 9) << 9) + pidx[(size_t)a * 4 + bc];
    }
    __syncthreads();

    // loss = 25 * mean((z1 - z2)^2) over 20 x 384 (exact fp32 z)
    float acc = 0.f;
    for (int pr = 0; pr < NGAMMA; ++pr) {
        const int a = sel[pr];
        const int j = selj[pr];
        const float* za = z + (size_t)a * ND;
        const float* zj = z + (size_t)j * ND;
        for (int d = t; d < ND; d += 256) {
            const float df = za[d] - zj[d];
            acc = fmaf(df, df, acc);
        }
    }
#pragma unroll
    for (int off = 1; off < 64; off <<= 1) acc += __shfl_xor(acc, off);
    if (lane == 0) red[w] = acc;
    __syncthreads();
    if (t == 0) {
        const float tot = red[0] + red[1] + red[2] + red[3];
        out[0] = 25.0f * tot / (float)(NGAMMA * ND);
        out[1] = ssum / (float)NGAMMA;
    }
}

extern "C" void kernel_launch(void* const* d_in, const int* in_sizes, int n_in,
                              void* d_out, int out_size, void* d_ws, size_t ws_size,
                              hipStream_t stream)
{
    const float* z    = (const float*)d_in[0];
    const int*   view = (const int*)d_in[1];
    float*       out  = (float*)d_out;
    char* ws = (char*)d_ws;

    // layout: zhi 48MB | pval 1MB | pidx 1MB | cval | cidx
    const size_t zhi_off  = 0;
    const size_t pval_off = (size_t)NB * NP * ND * 2;
    const size_t pidx_off = pval_off + (size_t)NB * NP * 4 * 4;
    const size_t cval_off = pidx_off + (size_t)NB * NP * 4 * 4;
    const size_t cidx_off = cval_off + 64 * NGAMMA * 4;

    unsigned short* zhi = (unsigned short*)(ws + zhi_off);
    float* pval = (float*)(ws + pval_off);
    int*   pidx = (int*)(ws + pidx_off);
    float* cval = (float*)(ws + cval_off);
    int*   cidx = (int*)(ws + cidx_off);

    fm_convert<<<(NB * NP * ND) / (8 * 256), 256, 0, stream>>>(z, zhi);
    fm_gemm<<<NB * 10, 256, 0, stream>>>(zhi, view, pval, pidx);
    fm_topk_local<<<(NB * NP) / 1024, 256, 0, stream>>>(pval, cval, cidx);
    fm_final<<<1, 256, 0, stream>>>(cval, cidx, pval, pidx, z, out);
}